// Round 19
// baseline (212.436 us; speedup 1.0000x reference)
//
#include <hip/hip_runtime.h>
#include <cstdint>

typedef _Float16 f16x8 __attribute__((ext_vector_type(8)));
typedef float    f32x4 __attribute__((ext_vector_type(4)));

#define E_TOTAL   1000000
#define N_NODES   100000
#define NROUNDS   3907      // ceil(1e6 / 256)
#define GRID_MAIN 512
#define SCL       2.8853900817779268f   // 2*log2(e), folded into W1..W3,b1..b3

// acc arrives pre-scaled by 2*log2(e):  tanh = 1 - 2/(1 + 2^acc)
__device__ __forceinline__ float tanh_pre(float a) {
  float e = __builtin_amdgcn_exp2f(a);
  return 1.0f - 2.0f * __builtin_amdgcn_rcpf(1.0f + e);
}
__device__ __forceinline__ float fast_sigmoid(float x) {
  float e = __builtin_amdgcn_exp2f(x * -1.4426950408889634f);
  return __builtin_amdgcn_rcpf(1.0f + e);
}
__device__ __forceinline__ uint32_t pack2(float a, float b) {
  return __builtin_bit_cast(uint32_t, __builtin_amdgcn_cvt_pkrtz(a, b));
}
__device__ __forceinline__ f16x8 asfrag(const uint32_t (&u)[4]) {
  uint4 v;
  v.x = u[0]; v.y = u[1]; v.z = u[2]; v.w = u[3];
  return __builtin_bit_cast(f16x8, v);
}
// async global->LDS, 16B per lane; global src per-lane, LDS dest = base + lane*16
__device__ __forceinline__ void gload_lds16(const void* g, void* l) {
  __builtin_amdgcn_global_load_lds(
      (const __attribute__((address_space(1))) void*)g,
      (__attribute__((address_space(3))) void*)(uintptr_t)l, 16, 0, 0);
}

// ---- setup kernel: x f32 -> f16 (row-major, 64 halves per node) ----
__global__ void kconv_x(const float* __restrict__ x, _Float16* __restrict__ xh) {
  int i = blockIdx.x * 256 + threadIdx.x;       // one thread per 8 elements
  if (i >= (N_NODES * 64) / 8) return;
  const float4* p = (const float4*)x + (size_t)i * 2;
  float4 a = p[0], b = p[1];
  f16x8 o = {(_Float16)a.x, (_Float16)a.y, (_Float16)a.z, (_Float16)a.w,
             (_Float16)b.x, (_Float16)b.y, (_Float16)b.z, (_Float16)b.w};
  *((f16x8*)xh + i) = o;
}

// ---- setup kernel: swizzle W1..W3 into A-fragment order, f16, pre-scaled ----
// frag(L,T,s): lane l, elem jj ->
//   SCL * W_L[k = 32s + 4*(l>>4) + (jj&3) + 16*(jj>>2)][n = 16T + (l&15)]
// stored at wswz[(((L*8+T)*4+s)*64 + l)*8 + jj]
__global__ void kswz_w(const float* __restrict__ W1, const float* __restrict__ W2,
                       const float* __restrict__ W3, _Float16* __restrict__ wswz) {
  int idx = blockIdx.x * 256 + threadIdx.x;     // 0..49151
  if (idx >= 49152) return;
  int jj = idx & 7;
  int l  = (idx >> 3) & 63;
  int s  = (idx >> 9) & 3;
  int T  = (idx >> 11) & 7;
  int L  = idx >> 14;
  int k  = 32 * s + 4 * (l >> 4) + (jj & 3) + 16 * (jj >> 2);
  int n  = 16 * T + (l & 15);
  const float* W = (L == 0) ? W1 : ((L == 1) ? W2 : W3);
  wswz[idx] = (_Float16)(W[k * 128 + n] * SCL);
}

// ---- setup kernel: biases (pre-scaled) + w4 into ws as f32 ----
__global__ void kprep_b(const float* __restrict__ b1, const float* __restrict__ b2,
                        const float* __restrict__ b3, const float* __restrict__ w4,
                        float* __restrict__ bscl) {
  int i = blockIdx.x * 256 + threadIdx.x;   // 0..511
  if (i >= 512) return;
  int r = i & 127;
  float v = (i < 128) ? b1[r] * SCL
          : (i < 256) ? b2[r] * SCL
          : (i < 384) ? b3[r] * SCL
          :             w4[r];
  bscl[i] = v;
}

// ---- one hidden layer (weights from LDS): Bin -> Bout, tanh fused ----
// L=0 reads lds_w[0..16383] (W1), L=1 reads lds_w[16384..32767] (W2).
template <int L>
__device__ __forceinline__ void mlp_layer(const _Float16* lds_w, const float* lds_b,
                                          int lane,
                                          const uint32_t (&Bin)[2][4][4],
                                          uint32_t (&Bout)[2][4][4]) {
  const int g = lane >> 4;
#pragma unroll
  for (int T = 0; T < 8; ++T) {
    const f32x4 bf = *(const f32x4*)(lds_b + L * 128 + T * 16 + g * 4);
    f32x4 acc0 = bf, acc1 = bf;
#pragma unroll
    for (int s = 0; s < 4; ++s) {
      const f16x8 W = *(const f16x8*)(lds_w + (size_t)(((L * 8 + T) * 4 + s) * 512) + lane * 8);
      acc0 = __builtin_amdgcn_mfma_f32_16x16x32_f16(W, asfrag(Bin[0][s]), acc0, 0, 0, 0);
      acc1 = __builtin_amdgcn_mfma_f32_16x16x32_f16(W, asfrag(Bin[1][s]), acc1, 0, 0, 0);
    }
    // D[f=16T+4g+r][edge] -> next-layer B frag: s'=T>>1, jj=(T&1)*4 + r
    const int si = T >> 1, d = (T & 1) * 2;
    Bout[0][si][d]     = pack2(tanh_pre(acc0[0]), tanh_pre(acc0[1]));
    Bout[0][si][d + 1] = pack2(tanh_pre(acc0[2]), tanh_pre(acc0[3]));
    Bout[1][si][d]     = pack2(tanh_pre(acc1[0]), tanh_pre(acc1[1]));
    Bout[1][si][d + 1] = pack2(tanh_pre(acc1[2]), tanh_pre(acc1[3]));
  }
}

// ---- layer 3 (tanh) + layer 4 dot(W4); W3 AND biases streamed from L1/L2
// (no LDS reads here: everything after the prefetch-issue point must be
//  LDS-free so the compiler can't insert alias-driven vmcnt waits)
__device__ __forceinline__ void mlp_out(const _Float16* __restrict__ gw3,
                                        const float* __restrict__ gb, int lane,
                                        const uint32_t (&Bin)[2][4][4],
                                        float (&dot)[2]) {
  const int g = lane >> 4;
  dot[0] = dot[1] = 0.f;
#pragma unroll
  for (int T = 0; T < 8; ++T) {
    const f32x4 bf = *(const f32x4*)(gb + T * 16 + g * 4);         // b3*SCL
    const f32x4 wf = *(const f32x4*)(gb + 128 + T * 16 + g * 4);   // w4
    f32x4 acc0 = bf, acc1 = bf;
#pragma unroll
    for (int s = 0; s < 4; ++s) {
      const f16x8 W = *(const f16x8*)(gw3 + (size_t)((T * 4 + s) * 512) + lane * 8);
      acc0 = __builtin_amdgcn_mfma_f32_16x16x32_f16(W, asfrag(Bin[0][s]), acc0, 0, 0, 0);
      acc1 = __builtin_amdgcn_mfma_f32_16x16x32_f16(W, asfrag(Bin[1][s]), acc1, 0, 0, 0);
    }
    dot[0] += tanh_pre(acc0[0]) * wf[0] + tanh_pre(acc0[1]) * wf[1]
            + tanh_pre(acc0[2]) * wf[2] + tanh_pre(acc0[3]) * wf[3];
    dot[1] += tanh_pre(acc1[0]) * wf[0] + tanh_pre(acc1[1]) * wf[1]
            + tanh_pre(acc1[2]) * wf[2] + tanh_pre(acc1[3]) * wf[3];
  }
}

// LDS map: [0,64K)=W1,W2 | [64K,65K)=b1,b2 (f32[256]) | [66560,+8K*wid)=gather buf
#define LDS_B_OFF   65536
#define LDS_G_OFF   66560
#define LDS_TOTAL   (66560 + 8 * 8192)   // 132096 B

template <bool XH>
__global__ __launch_bounds__(512)
__attribute__((amdgpu_num_vgpr(128)))
void edge_mlp(
    const int* __restrict__ eidx,
    const _Float16* __restrict__ xh,
    const float* __restrict__ xf,
    const _Float16* __restrict__ wswz,
    const float* __restrict__ bscl,
    float* __restrict__ out) {
  extern __shared__ char smem[];
  _Float16* lds_w = (_Float16*)smem;               // W1,W2: 64 KB
  float*    lds_b = (float*)(smem + LDS_B_OFF);    // b1|b2 : 256 f32
  const _Float16* gw3 = wswz + 32768;              // W3 fragments (L1/L2)
  const float*    gb  = bscl + 256;                // b3*SCL | w4 (L1)

  const int tid = threadIdx.x;
  {
    const uint4* src = (const uint4*)wswz;
    uint4* dst = (uint4*)smem;
#pragma unroll
    for (int i = 0; i < 8; ++i) dst[tid + i * 512] = src[tid + i * 512];
  }
  if (tid < 256) lds_b[tid] = bscl[tid];           // b1*SCL | b2*SCL
  __syncthreads();

  const float b4v = gb[256];                        // bscl[512]? no: see launch (b4 appended)
  const int wid = tid >> 6, lane = tid & 63;
  const int c = lane & 15, g = lane >> 4;
  char* gbuf = smem + LDS_G_OFF + wid * 8192;

  // indices for the FIRST round, then issue its data prefetch
  int pre_s[2], pre_d[2];
#pragma unroll
  for (int t = 0; t < 2; ++t) {
    int e  = blockIdx.x * 256 + wid * 32 + t * 16 + c;
    int ee = (e < E_TOTAL) ? e : 0;
    pre_s[t] = eidx[ee];
    pre_d[t] = eidx[E_TOTAL + ee];
  }
  if (XH) {
#pragma unroll
    for (int t = 0; t < 2; ++t) {
      const _Float16* ns = xh + (size_t)pre_s[t] * 64 + g * 8;
      const _Float16* nd = xh + (size_t)pre_d[t] * 64 + g * 8;
      char* cb = gbuf + t * 4096;
      gload_lds16(ns,      cb);
      gload_lds16(ns + 32, cb + 1024);
      gload_lds16(nd,      cb + 2048);
      gload_lds16(nd + 32, cb + 3072);
    }
  }

  for (int round = blockIdx.x; round < NROUNDS; round += GRID_MAIN) {
    const int ebase = round * 256 + wid * 32;

    uint32_t B0[2][4][4];   // [tile][s][dword]  (layer-1 B fragments)
    if (XH) {
      // prefetched data is ready once vmcnt drains
      asm volatile("s_waitcnt vmcnt(0)" ::: "memory");
      __builtin_amdgcn_sched_barrier(0);
#pragma unroll
      for (int t = 0; t < 2; ++t) {
        const char* cb = gbuf + t * 4096 + c * 16 + (g >> 1) * 256 + (g & 1) * 8;
#pragma unroll
        for (int n = 0; n < 2; ++n) {
#pragma unroll
          for (int sp = 0; sp < 2; ++sp) {
            const char* p = cb + (n * 2 + sp) * 1024;
            uint2 lo = *(const uint2*)(p);
            uint2 hi = *(const uint2*)(p + 512);
            B0[t][n * 2 + sp][0] = lo.x; B0[t][n * 2 + sp][1] = lo.y;
            B0[t][n * 2 + sp][2] = hi.x; B0[t][n * 2 + sp][3] = hi.y;
          }
        }
      }
    } else {
#pragma unroll
      for (int t = 0; t < 2; ++t) {
        int sN = pre_s[t];
        int dN = pre_d[t];
        const float* ps = xf + (size_t)sN * 64 + g * 4;
        const float* pd = xf + (size_t)dN * 64 + g * 4;
#pragma unroll
        for (int sp = 0; sp < 2; ++sp) {
#pragma unroll
          for (int h = 0; h < 2; ++h) {
            float4 fs = *(const float4*)(ps + sp * 32 + h * 16);
            float4 fd = *(const float4*)(pd + sp * 32 + h * 16);
            B0[t][sp][h * 2]         = pack2(fs.x, fs.y);
            B0[t][sp][h * 2 + 1]     = pack2(fs.z, fs.w);
            B0[t][2 + sp][h * 2]     = pack2(fd.x, fd.y);
            B0[t][2 + sp][h * 2 + 1] = pack2(fd.z, fd.w);
          }
        }
      }
    }

    // load NEXT round's edge indices now (consumed by the prefetch below)
    {
      int nr = round + GRID_MAIN;
      int base = (nr < NROUNDS) ? nr * 256 + wid * 32 : 0;
#pragma unroll
      for (int t = 0; t < 2; ++t) {
        int e  = base + t * 16 + c;
        int ee = (e < E_TOTAL) ? e : 0;
        pre_s[t] = eidx[ee];
        pre_d[t] = eidx[E_TOTAL + ee];
      }
    }

    uint32_t B1r[2][4][4], B2r[2][4][4];
    mlp_layer<0>(lds_w, lds_b, lane, B0, B1r);
    mlp_layer<1>(lds_w, lds_b, lane, B1r, B2r);

    // issue NEXT round's gather prefetch; it completes during layer 3
    if (XH) {
#pragma unroll
      for (int t = 0; t < 2; ++t) {
        const _Float16* ns = xh + (size_t)pre_s[t] * 64 + g * 8;
        const _Float16* nd = xh + (size_t)pre_d[t] * 64 + g * 8;
        char* cb = gbuf + t * 4096;
        gload_lds16(ns,      cb);
        gload_lds16(ns + 32, cb + 1024);
        gload_lds16(nd,      cb + 2048);
        gload_lds16(nd + 32, cb + 3072);
      }
    }

    float dot[2];
    mlp_out(gw3, gb, lane, B2r, dot);

#pragma unroll
    for (int t = 0; t < 2; ++t) {
      float v = dot[t];
      v += __shfl_xor(v, 16);
      v += __shfl_xor(v, 32);
      dot[t] = v;
    }
    if (g == 0) {
#pragma unroll
      for (int t = 0; t < 2; ++t) {
        int e = ebase + t * 16 + c;
        if (e < E_TOTAL) out[e] = fast_sigmoid(dot[t] + b4v);
      }
    }
    // keep cross-round scheduling pinned (R8 spill fix)
    __builtin_amdgcn_sched_barrier(0);
  }
}

extern "C" void kernel_launch(void* const* d_in, const int* in_sizes, int n_in,
                              void* d_out, int out_size, void* d_ws, size_t ws_size,
                              hipStream_t stream) {
  (void)in_sizes; (void)n_in; (void)out_size;
  const float* x  = (const float*)d_in[0];
  const int* eidx = (const int*)d_in[1];
  const float* W1 = (const float*)d_in[2];
  const float* b1 = (const float*)d_in[3];
  const float* W2 = (const float*)d_in[4];
  const float* b2 = (const float*)d_in[5];
  const float* W3 = (const float*)d_in[6];
  const float* b3 = (const float*)d_in[7];
  const float* w4 = (const float*)d_in[8];
  const float* b4 = (const float*)d_in[9];
  float* out = (float*)d_out;

  const size_t XH_BYTES   = (size_t)N_NODES * 64 * 2;   // 12.8 MB
  const size_t WS_W_BYTES = 49152 * 2;                  // 96 KB
  const size_t WS_B_BYTES = (512 + 4) * 4;              // bscl[512] + b4 copy
  const bool xh_ok = ws_size >= XH_BYTES + WS_W_BYTES + WS_B_BYTES;

  _Float16* ws_xh = (_Float16*)d_ws;
  _Float16* ws_w  = (_Float16*)((char*)d_ws + (xh_ok ? XH_BYTES : 0));
  float*    bscl  = (float*)((char*)ws_w + WS_W_BYTES);

  kswz_w<<<192, 256, 0, stream>>>(W1, W2, W3, ws_w);
  kprep_b<<<2, 256, 0, stream>>>(b1, b2, b3, w4, bscl);
  // bscl[512] = b4 scalar (copied via tiny async memcpy)
  hipMemcpyAsync(bscl + 512, b4, 4, hipMemcpyDeviceToDevice, stream);
  if (xh_ok) kconv_x<<<3125, 256, 0, stream>>>(x, ws_xh);

  if (xh_ok) {
    edge_mlp<true><<<GRID_MAIN, 512, LDS_TOTAL, stream>>>(
        eidx, ws_xh, x, ws_w, bscl, out);
  } else {
    edge_mlp<false><<<GRID_MAIN, 512, LDS_TOTAL, stream>>>(
        eidx, ws_xh, x, ws_w, bscl, out);
  }
}

// Round 20
// 145.326 us; speedup vs baseline: 1.4618x; 1.4618x over previous
//
#include <hip/hip_runtime.h>
#include <cstdint>

typedef _Float16 f16x8  __attribute__((ext_vector_type(8)));
typedef _Float16 f16x16 __attribute__((ext_vector_type(16)));
typedef float    f32x4  __attribute__((ext_vector_type(4)));

#define E_TOTAL   1000000
#define N_NODES   100000
#define NROUNDS   3907      // ceil(1e6 / 256)
#define GRID_MAIN 512
#define SCL       2.8853900817779268f   // 2*log2(e), folded into W1..W3,b1..b3

// acc arrives pre-scaled by 2*log2(e):  tanh = 1 - 2/(1 + 2^acc)
__device__ __forceinline__ float tanh_pre(float a) {
  float e = __builtin_amdgcn_exp2f(a);
  return 1.0f - 2.0f * __builtin_amdgcn_rcpf(1.0f + e);
}
__device__ __forceinline__ float fast_sigmoid(float x) {
  float e = __builtin_amdgcn_exp2f(x * -1.4426950408889634f);
  return __builtin_amdgcn_rcpf(1.0f + e);
}
__device__ __forceinline__ uint32_t pack2(float a, float b) {
  return __builtin_bit_cast(uint32_t, __builtin_amdgcn_cvt_pkrtz(a, b));
}
__device__ __forceinline__ f16x8 asfrag(const uint32_t (&u)[4]) {
  uint4 v;
  v.x = u[0]; v.y = u[1]; v.z = u[2]; v.w = u[3];
  return __builtin_bit_cast(f16x8, v);
}

// ---- setup kernel: x f32 -> f16, PER-NODE FRAGMENT-ORDER layout ----
// new[n*64 + g*16 + f*4 + j] = (f16)x[n*64 + f*16 + 4g + j],  g,f in 0..3, j in 0..3
// so lane (c,g)'s two B-fragments for node n are the 32 contiguous bytes at
// xh + n*64 + g*16:  uint4 #0 = fragment s=0, uint4 #1 = fragment s=1.
__global__ void kconv_x(const float* __restrict__ x, _Float16* __restrict__ xh) {
  int idx = blockIdx.x * 256 + threadIdx.x;     // one thread per (node, g)
  if (idx >= N_NODES * 4) return;
  int n = idx >> 2, g = idx & 3;
  const float* src = x + (size_t)n * 64 + 4 * g;
  f16x16 o;
#pragma unroll
  for (int f = 0; f < 4; ++f) {
    float4 v = *(const float4*)(src + f * 16);
    o[f * 4 + 0] = (_Float16)v.x;
    o[f * 4 + 1] = (_Float16)v.y;
    o[f * 4 + 2] = (_Float16)v.z;
    o[f * 4 + 3] = (_Float16)v.w;
  }
  *(f16x16*)(xh + (size_t)n * 64 + g * 16) = o;
}

// ---- setup kernel: swizzle W1..W3 into A-fragment order, f16, pre-scaled ----
// frag(L,T,s): lane l, elem jj ->
//   SCL * W_L[k = 32s + 4*(l>>4) + (jj&3) + 16*(jj>>2)][n = 16T + (l&15)]
// stored at wswz[(((L*8+T)*4+s)*64 + l)*8 + jj]
__global__ void kswz_w(const float* __restrict__ W1, const float* __restrict__ W2,
                       const float* __restrict__ W3, _Float16* __restrict__ wswz) {
  int idx = blockIdx.x * 256 + threadIdx.x;     // 0..49151
  if (idx >= 49152) return;
  int jj = idx & 7;
  int l  = (idx >> 3) & 63;
  int s  = (idx >> 9) & 3;
  int T  = (idx >> 11) & 7;
  int L  = idx >> 14;
  int k  = 32 * s + 4 * (l >> 4) + (jj & 3) + 16 * (jj >> 2);
  int n  = 16 * T + (l & 15);
  const float* W = (L == 0) ? W1 : ((L == 1) ? W2 : W3);
  wswz[idx] = (_Float16)(W[k * 128 + n] * SCL);
}

// ---- one hidden layer (weights from LDS): Bin -> Bout, tanh fused ----
// L=0 reads lds_w[0..16383] (W1), L=1 reads lds_w[16384..32767] (W2).
template <int L>
__device__ __forceinline__ void mlp_layer(const _Float16* lds_w, const float* lds_b,
                                          int lane,
                                          const uint32_t (&Bin)[2][4][4],
                                          uint32_t (&Bout)[2][4][4]) {
  const int g = lane >> 4;
#pragma unroll
  for (int T = 0; T < 8; ++T) {
    const f32x4 bf = *(const f32x4*)(lds_b + L * 128 + T * 16 + g * 4);
    f32x4 acc0 = bf, acc1 = bf;
#pragma unroll
    for (int s = 0; s < 4; ++s) {
      const f16x8 W = *(const f16x8*)(lds_w + (size_t)(((L * 8 + T) * 4 + s) * 512) + lane * 8);
      acc0 = __builtin_amdgcn_mfma_f32_16x16x32_f16(W, asfrag(Bin[0][s]), acc0, 0, 0, 0);
      acc1 = __builtin_amdgcn_mfma_f32_16x16x32_f16(W, asfrag(Bin[1][s]), acc1, 0, 0, 0);
    }
    // D[f=16T+4g+r][edge] -> next-layer B frag: s'=T>>1, jj=(T&1)*4 + r
    const int si = T >> 1, d = (T & 1) * 2;
    Bout[0][si][d]     = pack2(tanh_pre(acc0[0]), tanh_pre(acc0[1]));
    Bout[0][si][d + 1] = pack2(tanh_pre(acc0[2]), tanh_pre(acc0[3]));
    Bout[1][si][d]     = pack2(tanh_pre(acc1[0]), tanh_pre(acc1[1]));
    Bout[1][si][d + 1] = pack2(tanh_pre(acc1[2]), tanh_pre(acc1[3]));
  }
}

// ---- layer 3 (tanh) fused with layer 4 dot(W4); W3 streamed from L1/L2 ----
__device__ __forceinline__ void mlp_out(const _Float16* __restrict__ gw3,
                                        const float* lds_b, int lane,
                                        const uint32_t (&Bin)[2][4][4],
                                        float (&dot)[2]) {
  const int g = lane >> 4;
  dot[0] = dot[1] = 0.f;
#pragma unroll
  for (int T = 0; T < 8; ++T) {
    const f32x4 bf = *(const f32x4*)(lds_b + 256 + T * 16 + g * 4);
    const f32x4 wf = *(const f32x4*)(lds_b + 384 + T * 16 + g * 4);
    f32x4 acc0 = bf, acc1 = bf;
#pragma unroll
    for (int s = 0; s < 4; ++s) {
      const f16x8 W = *(const f16x8*)(gw3 + (size_t)((T * 4 + s) * 512) + lane * 8);
      acc0 = __builtin_amdgcn_mfma_f32_16x16x32_f16(W, asfrag(Bin[0][s]), acc0, 0, 0, 0);
      acc1 = __builtin_amdgcn_mfma_f32_16x16x32_f16(W, asfrag(Bin[1][s]), acc1, 0, 0, 0);
    }
    dot[0] += tanh_pre(acc0[0]) * wf[0] + tanh_pre(acc0[1]) * wf[1]
            + tanh_pre(acc0[2]) * wf[2] + tanh_pre(acc0[3]) * wf[3];
    dot[1] += tanh_pre(acc1[0]) * wf[0] + tanh_pre(acc1[1]) * wf[1]
            + tanh_pre(acc1[2]) * wf[2] + tanh_pre(acc1[3]) * wf[3];
  }
}

template <bool XH>
__global__ __launch_bounds__(512)
__attribute__((amdgpu_num_vgpr(128)))
void edge_mlp(
    const int* __restrict__ eidx,
    const _Float16* __restrict__ xh,
    const float* __restrict__ xf,
    const _Float16* __restrict__ wswz,
    const float* __restrict__ b1, const float* __restrict__ b2,
    const float* __restrict__ b3, const float* __restrict__ w4,
    const float* __restrict__ b4g,
    float* __restrict__ out) {
  extern __shared__ char smem[];
  _Float16* lds_w = (_Float16*)smem;            // W1,W2: 32768 halves = 64 KB
  float*    lds_b = (float*)(smem + 65536);     // b1|b2|b3|w4 : 512 f32
  const _Float16* gw3 = wswz + 32768;           // W3 fragments stay in L1/L2

  const int tid = threadIdx.x;
  {
    const uint4* src = (const uint4*)wswz;
    uint4* dst = (uint4*)smem;
#pragma unroll
    for (int i = 0; i < 8; ++i) dst[tid + i * 512] = src[tid + i * 512];
  }
  if (tid < 128) {
    lds_b[tid]       = b1[tid] * SCL;
    lds_b[128 + tid] = b2[tid] * SCL;
    lds_b[256 + tid] = b3[tid] * SCL;
    lds_b[384 + tid] = w4[tid];
  }
  __syncthreads();

  const float b4v = b4g[0];
  const int wid = tid >> 6, lane = tid & 63;
  const int c = lane & 15, g = lane >> 4;

  // prefetch first round's edge indices (hide eidx L2 latency under compute)
  int pre_s[2], pre_d[2];
#pragma unroll
  for (int t = 0; t < 2; ++t) {
    int e  = blockIdx.x * 256 + wid * 32 + t * 16 + c;
    int ee = (e < E_TOTAL) ? e : 0;
    pre_s[t] = eidx[ee];
    pre_d[t] = eidx[E_TOTAL + ee];
  }

  for (int round = blockIdx.x; round < NROUNDS; round += GRID_MAIN) {
    const int ebase = round * 256 + wid * 32;

    uint32_t B0[2][4][4];   // [tile][s][dword]  (layer-1 B fragments)
#pragma unroll
    for (int t = 0; t < 2; ++t) {
      int sN = pre_s[t];
      int dN = pre_d[t];
      if (XH) {
        // fragment-order layout: 32 contiguous bytes per (node, g)
        const uint4* ps = (const uint4*)(xh + (size_t)sN * 64 + g * 16);
        const uint4* pd = (const uint4*)(xh + (size_t)dN * 64 + g * 16);
        uint4 a0 = ps[0], a1 = ps[1];
        uint4 d0 = pd[0], d1 = pd[1];
        B0[t][0][0] = a0.x; B0[t][0][1] = a0.y; B0[t][0][2] = a0.z; B0[t][0][3] = a0.w;
        B0[t][1][0] = a1.x; B0[t][1][1] = a1.y; B0[t][1][2] = a1.z; B0[t][1][3] = a1.w;
        B0[t][2][0] = d0.x; B0[t][2][1] = d0.y; B0[t][2][2] = d0.z; B0[t][2][3] = d0.w;
        B0[t][3][0] = d1.x; B0[t][3][1] = d1.y; B0[t][3][2] = d1.z; B0[t][3][3] = d1.w;
      } else {
        const float* ps = xf + (size_t)sN * 64 + g * 4;
        const float* pd = xf + (size_t)dN * 64 + g * 4;
#pragma unroll
        for (int sp = 0; sp < 2; ++sp) {
#pragma unroll
          for (int h = 0; h < 2; ++h) {
            float4 fs = *(const float4*)(ps + sp * 32 + h * 16);
            float4 fd = *(const float4*)(pd + sp * 32 + h * 16);
            B0[t][sp][h * 2]         = pack2(fs.x, fs.y);
            B0[t][sp][h * 2 + 1]     = pack2(fs.z, fs.w);
            B0[t][2 + sp][h * 2]     = pack2(fd.x, fd.y);
            B0[t][2 + sp][h * 2 + 1] = pack2(fd.z, fd.w);
          }
        }
      }
    }

    // issue next round's index loads now — they complete during the 3 layers
    {
      int nr = round + GRID_MAIN;
      if (nr < NROUNDS) {
#pragma unroll
        for (int t = 0; t < 2; ++t) {
          int e  = nr * 256 + wid * 32 + t * 16 + c;
          int ee = (e < E_TOTAL) ? e : 0;
          pre_s[t] = eidx[ee];
          pre_d[t] = eidx[E_TOTAL + ee];
        }
      }
    }

    uint32_t B1r[2][4][4], B2r[2][4][4];
    mlp_layer<0>(lds_w, lds_b, lane, B0, B1r);
    mlp_layer<1>(lds_w, lds_b, lane, B1r, B2r);

    float dot[2];
    mlp_out(gw3, lds_b, lane, B2r, dot);

#pragma unroll
    for (int t = 0; t < 2; ++t) {
      float v = dot[t];
      v += __shfl_xor(v, 16);
      v += __shfl_xor(v, 32);
      dot[t] = v;
    }
    if (g == 0) {
#pragma unroll
      for (int t = 0; t < 2; ++t) {
        int e = ebase + t * 16 + c;
        if (e < E_TOTAL) out[e] = fast_sigmoid(dot[t] + b4v);
      }
    }
    // stop the scheduler from software-pipelining next round's gather
    // into this round's compute (R8: this is what eliminated the
    // register-budget overflow spills — keep it). Index prefetch above
    // is the controlled, +4-reg subset of that pipelining.
    __builtin_amdgcn_sched_barrier(0);
  }
}

extern "C" void kernel_launch(void* const* d_in, const int* in_sizes, int n_in,
                              void* d_out, int out_size, void* d_ws, size_t ws_size,
                              hipStream_t stream) {
  (void)in_sizes; (void)n_in; (void)out_size;
  const float* x  = (const float*)d_in[0];
  const int* eidx = (const int*)d_in[1];
  const float* W1 = (const float*)d_in[2];
  const float* b1 = (const float*)d_in[3];
  const float* W2 = (const float*)d_in[4];
  const float* b2 = (const float*)d_in[5];
  const float* W3 = (const float*)d_in[6];
  const float* b3 = (const float*)d_in[7];
  const float* w4 = (const float*)d_in[8];
  const float* b4 = (const float*)d_in[9];
  float* out = (float*)d_out;

  const size_t XH_BYTES   = (size_t)N_NODES * 64 * 2;  // 12.8 MB
  const size_t WS_W_BYTES = 49152 * 2;
  const bool xh_ok = ws_size >= XH_BYTES + WS_W_BYTES;

  _Float16* ws_xh = (_Float16*)d_ws;
  _Float16* ws_w  = (_Float16*)((char*)d_ws + (xh_ok ? XH_BYTES : 0));

  kswz_w<<<192, 256, 0, stream>>>(W1, W2, W3, ws_w);
  if (xh_ok) kconv_x<<<1563, 256, 0, stream>>>(x, ws_xh);   // 400000 threads

  // W1,W2 in LDS (64 KB) + biases; W3 from L1/L2.
  const size_t lds_bytes = 65536 + 2048;
  if (xh_ok) {
    edge_mlp<true><<<GRID_MAIN, 512, lds_bytes, stream>>>(
        eidx, ws_xh, x, ws_w, b1, b2, b3, w4, b4, out);
  } else {
    edge_mlp<false><<<GRID_MAIN, 512, lds_bytes, stream>>>(
        eidx, ws_xh, x, ws_w, b1, b2, b3, w4, b4, out);
  }
}